// Round 14
// baseline (101.626 us; speedup 1.0000x reference)
//
#include <hip/hip_runtime.h>
#include <cstdint>

typedef _Float16 half2_t __attribute__((ext_vector_type(2)));
typedef _Float16 half4_t __attribute__((ext_vector_type(4)));
typedef _Float16 half8_t __attribute__((ext_vector_type(8)));
typedef float floatx4 __attribute__((ext_vector_type(4)));

#define T_SEQ 4096
#define D_HEAD 128
#define SCALE_LOG2 0.12751742526f  // log2(e)/sqrt(128), folded into q at proj time

__device__ __forceinline__ void gload16(const void* src, void* dst_lds) {
    using gptr_t = const __attribute__((address_space(1))) unsigned int*;
    using lptr_t = __attribute__((address_space(3))) unsigned int*;
    __builtin_amdgcn_global_load_lds((gptr_t)(uintptr_t)src,
                                     (lptr_t)(unsigned int)(uintptr_t)dst_lds, 16, 0, 0);
}

__device__ __forceinline__ float exp2_raw(float x) {
#if __has_builtin(__builtin_amdgcn_exp2f)
    return __builtin_amdgcn_exp2f(x);   // raw v_exp_f32
#else
    return exp2f(x);
#endif
}

// ---------------- QKV projection (MFMA f16, fp32 accumulate) ----------------
__global__ __launch_bounds__(256) void proj_kernel(
    const float* __restrict__ x,
    const float* __restrict__ Wq, const float* __restrict__ bq,
    const float* __restrict__ Wk, const float* __restrict__ bk,
    const float* __restrict__ Wv, const float* __restrict__ bv,
    _Float16* __restrict__ qf, _Float16* __restrict__ kf, _Float16* __restrict__ vt)
{
    __shared__ __align__(16) _Float16 Ws[128 * 136];
    __shared__ __align__(16) _Float16 xs[64 * 136];

    const int t = threadIdx.x;
    const int mat = blockIdx.y;
    const float* W = (mat == 0) ? Wq : (mat == 1) ? Wk : Wv;
    const float* bias = (mat == 0) ? bq : (mat == 1) ? bk : bv;
    const float osc = (mat == 0) ? SCALE_LOG2 : 1.0f;
    const int r0 = blockIdx.x * 64;

    {
        const int o = t >> 1;
        const int i0 = (t & 1) * 64;
        for (int jj = 0; jj < 8; ++jj) {
            floatx4 w0 = *reinterpret_cast<const floatx4*>(W + o * 128 + i0 + jj * 8);
            floatx4 w1 = *reinterpret_cast<const floatx4*>(W + o * 128 + i0 + jj * 8 + 4);
            half8_t h;
            h[0]=(_Float16)w0[0]; h[1]=(_Float16)w0[1]; h[2]=(_Float16)w0[2]; h[3]=(_Float16)w0[3];
            h[4]=(_Float16)w1[0]; h[5]=(_Float16)w1[1]; h[6]=(_Float16)w1[2]; h[7]=(_Float16)w1[3];
            *reinterpret_cast<half8_t*>(&Ws[o * 136 + i0 + jj * 8]) = h;
        }
    }
    {
        const int row = t >> 2;
        const int c0 = (t & 3) * 32;
        for (int jj = 0; jj < 4; ++jj) {
            floatx4 w0 = *reinterpret_cast<const floatx4*>(x + (size_t)(r0 + row) * 128 + c0 + jj * 8);
            floatx4 w1 = *reinterpret_cast<const floatx4*>(x + (size_t)(r0 + row) * 128 + c0 + jj * 8 + 4);
            half8_t h;
            h[0]=(_Float16)w0[0]; h[1]=(_Float16)w0[1]; h[2]=(_Float16)w0[2]; h[3]=(_Float16)w0[3];
            h[4]=(_Float16)w1[0]; h[5]=(_Float16)w1[1]; h[6]=(_Float16)w1[2]; h[7]=(_Float16)w1[3];
            *reinterpret_cast<half8_t*>(&xs[row * 136 + c0 + jj * 8]) = h;
        }
    }
    __syncthreads();

    const int w = t >> 6;
    const int lane = t & 63;
    const int lo = lane & 15, hi = lane >> 4;

    floatx4 acc[8] = {};
    for (int dc = 0; dc < 4; ++dc) {
        half8_t a8 = *reinterpret_cast<const half8_t*>(&xs[(w * 16 + lo) * 136 + dc * 32 + hi * 8]);
        for (int ot = 0; ot < 8; ++ot) {
            half8_t b8 = *reinterpret_cast<const half8_t*>(&Ws[(ot * 16 + lo) * 136 + dc * 32 + hi * 8]);
            acc[ot] = __builtin_amdgcn_mfma_f32_16x16x32_f16(a8, b8, acc[ot], 0, 0, 0);
        }
    }
    __syncthreads();

    float bb[8];
    for (int ot = 0; ot < 8; ++ot) bb[ot] = bias[ot * 16 + lo];

    if (mat < 2) {
        _Float16* ol = xs;
        for (int ot = 0; ot < 8; ++ot)
            for (int r = 0; r < 4; ++r)
                ol[(w * 16 + hi * 4 + r) * 136 + ot * 16 + lo] = (_Float16)((acc[ot][r] + bb[ot]) * osc);
        __syncthreads();
        _Float16* dst = (mat == 0) ? qf : kf;
        for (int i = 0; i < 4; ++i) {
            int c = t + 256 * i;
            int row = c >> 4, p = c & 15;
            half8_t v = *reinterpret_cast<const half8_t*>(&ol[row * 136 + p * 8]);
            *reinterpret_cast<half8_t*>(dst + (size_t)(r0 + row) * 128 + p * 8) = v;
        }
    } else {
        _Float16* vl = Ws;  // [128][72]
        for (int ot = 0; ot < 8; ++ot)
            for (int r = 0; r < 4; ++r)
                vl[(ot * 16 + lo) * 72 + w * 16 + hi * 4 + r] = (_Float16)(acc[ot][r] + bb[ot]);
        __syncthreads();
        const int b = r0 >> 12, tl0 = r0 & 4095;
        for (int i = 0; i < 4; ++i) {
            int c = t + 256 * i;
            int d = c >> 3, p = c & 7;
            half8_t v = *reinterpret_cast<const half8_t*>(&vl[d * 72 + p * 8]);
            *reinterpret_cast<half8_t*>(vt + ((size_t)(b * 128 + d)) * 4096 + tl0 + p * 8) = v;
        }
    }
}

// ---------------- flash attention: barrier-free per-wave-private pipeline ----------------
// 256 blocks x 512 threads = 8 waves: 2 q-groups (32 q as 2x16) x 4 kv-splits (16 kv).
// kv tile = 64. EACH WAVE owns a private 18KB LDS region: K 2x4KB (16 rows x 256B,
// swizzled, via global_load_lds) + V 2x5KB (128 d-rows x 32B padded to 40B -> PV
// ds_read_b64 conflict-free). A wave only ever reads its OWN staged data ->
// ZERO __syncthreads() in the main loop; ordering is one s_waitcnt vmcnt(8) per tile
// (prev tile's K-DMA) + compiler register-dependency waits for the V regs.
__global__ __launch_bounds__(512, 1) void attn_kernel(
    const _Float16* __restrict__ qf, const _Float16* __restrict__ kf,
    const _Float16* __restrict__ vt, float* __restrict__ out)
{
    __shared__ __align__(16) char smem[147456];   // 8 waves x 18432B private

    const int tid = threadIdx.x;
    const int w = tid >> 6, lane = tid & 63;
    const int lo = lane & 15, hi = lane >> 4;
    const int qg = w & 1, ksp = w >> 1;

    // XCD-aware swizzle: 32 consecutive wg per XCD -> one batch's K/V per XCD L2
    const int bx = blockIdx.x;
    const int wg = (bx & 7) * 32 + (bx >> 3);
    const int b = wg >> 6;
    const int q0 = (wg & 63) * 64;

    const char* kbc = (const char*)(kf + (size_t)b * T_SEQ * 128);
    const char* vbc = (const char*)(vt + (size_t)b * 128 * T_SEQ);

    char* const wbase = smem + w * 18432;
    char* const Kb0 = wbase;            // K buffers: 4096B each
    char* const Kb1 = wbase + 4096;
    char* const Vb0 = wbase + 8192;     // V buffers: 128 x 40B = 5120B each
    char* const Vb1 = wbase + 13312;

    // K staging: private 16 rows x 256B. LDS[r][slot] = K[ksp*16+r][slot ^ (r&7)].
    int koff[4], kdst[4];
#pragma unroll
    for (int r = 0; r < 4; ++r) {
        int rl = r * 4 + (lane >> 4);
        koff[r] = (ksp * 16 + rl) * 256 + (((lane & 15) ^ (rl & 7)) << 4);
        kdst[r] = r * 1024 + lane * 16;
    }
    // V staging: lane loads uint4 at d=(lane>>1)+32i, 16B half h=lane&1; LDS row pad 40B.
    int vsrc[4], vdst[4];
#pragma unroll
    for (int i = 0; i < 4; ++i) {
        int d = (lane >> 1) + 32 * i;
        vsrc[i] = d * (T_SEQ * 2) + ksp * 32 + (lane & 1) * 16;
        vdst[i] = d * 40 + (lane & 1) * 16;
    }
    // LDS read offsets (loop-invariant)
    int kro[4];
#pragma unroll
    for (int dc = 0; dc < 4; ++dc)
        kro[dc] = lo * 256 + (((dc * 4 + hi) ^ (lo & 7)) << 4);
    int vro[8];
#pragma unroll
    for (int dt = 0; dt < 8; ++dt)
        vro[dt] = (dt * 16 + lo) * 40 + hi * 8;   // banks 10*lo+2*hi: conflict-free

    // Q fragments (pre-scaled by log2(e)/sqrt(D)): d-enum dc*32+hi*8+j matches K-side
    half8_t qfA[4], qfB[4];
    {
        const _Float16* qa = qf + ((size_t)b * T_SEQ + q0 + qg * 32 + lo) * 128;
        const _Float16* qb = qa + 16 * 128;
#pragma unroll
        for (int dc = 0; dc < 4; ++dc) {
            qfA[dc] = *reinterpret_cast<const half8_t*>(qa + dc * 32 + hi * 8);
            qfB[dc] = *reinterpret_cast<const half8_t*>(qb + dc * 32 + hi * 8);
        }
    }

    floatx4 accA[8] = {}, accB[8] = {};
    float mA = -1e30f, mB = -1e30f, lA = 0.f, lB = 0.f;   // l is LANE-PARTIAL
    half4_t paA = {}, paB = {};                           // P of previous tile

#define VSTORE(VBUF, VR) do {                                                          \
    _Pragma("unroll")                                                                  \
    for (int i = 0; i < 4; ++i) {                                                      \
        *reinterpret_cast<uint2*>((VBUF) + vdst[i]) = make_uint2(VR[i].x, VR[i].y);    \
        *reinterpret_cast<uint2*>((VBUF) + vdst[i] + 8) = make_uint2(VR[i].z, VR[i].w);\
    }                                                                                  \
} while (0)

    // prologue: K(0) -> Kb0 (issued first!), V(0) -> regs -> Vb0
#pragma unroll
    for (int r = 0; r < 4; ++r) gload16(kbc + koff[r], Kb0 + kdst[r]);
    {
        uint4 vr[4];
#pragma unroll
        for (int i = 0; i < 4; ++i) vr[i] = *reinterpret_cast<const uint4*>(vbc + vsrc[i]);
        VSTORE(Vb0, vr);   // compiler's vr-wait drains K(0) too (older)
    }

    // Per tile t: [issue K(t+1) FIRST, then V(t+1)->regs] [vmcnt(8): K(t) ready]
    //   [QK(t)] [lane-local defer-max] [PV(t-1) from VOTH] [V regs -> VOTH] [pa(t)]
    // V(t-1) and V(t+1) share a buffer (same parity); read-then-write is same-wave
    // program order. No barriers.
#define TILE(T0, KCUR, KNXT, VOTH, PF, DOPREV) do {                                    \
    uint4 vr[4];                                                                       \
    if (PF) {                                                                          \
        const char* ks = kbc + (size_t)((T0) + 1) * 16384;                             \
        _Pragma("unroll")                                                              \
        for (int r = 0; r < 4; ++r) gload16(ks + koff[r], (KNXT) + kdst[r]);           \
        const char* vs = vbc + (size_t)((T0) + 1) * 128;                               \
        _Pragma("unroll")                                                              \
        for (int i = 0; i < 4; ++i)                                                    \
            vr[i] = *reinterpret_cast<const uint4*>(vs + vsrc[i]);                     \
        asm volatile("s_waitcnt vmcnt(8)" ::: "memory");                               \
    } else {                                                                           \
        asm volatile("s_waitcnt vmcnt(0)" ::: "memory");                               \
    }                                                                                  \
    __builtin_amdgcn_sched_barrier(0);                                                 \
    floatx4 sA = {0.f,0.f,0.f,0.f}, sB = {0.f,0.f,0.f,0.f};                            \
    __builtin_amdgcn_s_setprio(1);                                                     \
    _Pragma("unroll")                                                                  \
    for (int dc = 0; dc < 4; ++dc) {                                                   \
        half8_t kf8 = *reinterpret_cast<const half8_t*>((KCUR) + kro[dc]);             \
        sA = __builtin_amdgcn_mfma_f32_16x16x32_f16(kf8, qfA[dc], sA, 0, 0, 0);        \
        sB = __builtin_amdgcn_mfma_f32_16x16x32_f16(kf8, qfB[dc], sB, 0, 0, 0);        \
    }                                                                                  \
    __builtin_amdgcn_s_setprio(0);                                                     \
    float mpA = fmaxf(fmaxf(sA[0], sA[1]), fmaxf(sA[2], sA[3]));                       \
    float mpB = fmaxf(fmaxf(sB[0], sB[1]), fmaxf(sB[2], sB[3]));                       \
    bool ok = (mpA <= mA + 4.0f) && (mpB <= mB + 4.0f);                                \
    if (!__all(ok)) {                                                                  \
        float ra = mpA, rb = mpB;                                                      \
        ra = fmaxf(ra, __shfl_xor(ra, 16)); ra = fmaxf(ra, __shfl_xor(ra, 32));        \
        rb = fmaxf(rb, __shfl_xor(rb, 16)); rb = fmaxf(rb, __shfl_xor(rb, 32));        \
        float nA = fmaxf(mA, ra), nB = fmaxf(mB, rb);                                  \
        float aA = exp2_raw(mA - nA), aB = exp2_raw(mB - nB);                          \
        lA *= aA; lB *= aB;                                                            \
        _Pragma("unroll")                                                              \
        for (int dt = 0; dt < 8; ++dt) { accA[dt] *= aA; accB[dt] *= aB; }             \
        mA = nA; mB = nB;                                                              \
    }                                                                                  \
    if (DOPREV) {                                                                      \
        __builtin_amdgcn_s_setprio(1);                                                 \
        _Pragma("unroll")                                                              \
        for (int dt = 0; dt < 8; ++dt) {                                               \
            half4_t vfr = *reinterpret_cast<const half4_t*>((VOTH) + vro[dt]);         \
            accA[dt] = __builtin_amdgcn_mfma_f32_16x16x16f16(vfr, paA, accA[dt], 0, 0, 0); \
            accB[dt] = __builtin_amdgcn_mfma_f32_16x16x16f16(vfr, paB, accB[dt], 0, 0, 0); \
        }                                                                              \
        __builtin_amdgcn_s_setprio(0);                                                 \
    }                                                                                  \
    if (PF) VSTORE(VOTH, vr);                                                          \
    {                                                                                  \
        float p0 = exp2_raw(sA[0] - mA), p1 = exp2_raw(sA[1] - mA);                    \
        float p2 = exp2_raw(sA[2] - mA), p3 = exp2_raw(sA[3] - mA);                    \
        lA += (p0 + p1) + (p2 + p3);                                                   \
        half2_t h0 = __builtin_bit_cast(half2_t, __builtin_amdgcn_cvt_pkrtz(p0, p1));  \
        half2_t h1 = __builtin_bit_cast(half2_t, __builtin_amdgcn_cvt_pkrtz(p2, p3));  \
        paA[0] = h0[0]; paA[1] = h0[1]; paA[2] = h1[0]; paA[3] = h1[1];                \
        p0 = exp2_raw(sB[0] - mB); p1 = exp2_raw(sB[1] - mB);                          \
        p2 = exp2_raw(sB[2] - mB); p3 = exp2_raw(sB[3] - mB);                          \
        lB += (p0 + p1) + (p2 + p3);                                                   \
        h0 = __builtin_bit_cast(half2_t, __builtin_amdgcn_cvt_pkrtz(p0, p1));          \
        h1 = __builtin_bit_cast(half2_t, __builtin_amdgcn_cvt_pkrtz(p2, p3));          \
        paB[0] = h0[0]; paB[1] = h0[1]; paB[2] = h1[0]; paB[3] = h1[1];                \
    }                                                                                  \
} while (0)

    // 64 tiles of 64 kv. K(t) in Kb[t&1]; V(t) in Vb[t&1].
    TILE(0, Kb0, Kb1, Vb1, 1, 0);
    for (int tt = 1; tt < 62; tt += 2) {
        TILE(tt,     Kb1, Kb0, Vb0, 1, 1);
        TILE(tt + 1, Kb0, Kb1, Vb1, 1, 1);
    }
    TILE(63, Kb1, Kb0, Vb0, 0, 1);
#undef TILE

    // epilogue: PV of tile 63 (V(63) in Vb1)
#pragma unroll
    for (int dt = 0; dt < 8; ++dt) {
        half4_t vfr = *reinterpret_cast<const half4_t*>(Vb1 + vro[dt]);
        accA[dt] = __builtin_amdgcn_mfma_f32_16x16x16f16(vfr, paA, accA[dt], 0, 0, 0);
        accB[dt] = __builtin_amdgcn_mfma_f32_16x16x16f16(vfr, paB, accB[dt], 0, 0, 0);
    }

    // reduce lane-partial l across hi-groups (once)
    lA += __shfl_xor(lA, 16); lA += __shfl_xor(lA, 32);
    lB += __shfl_xor(lB, 16); lB += __shfl_xor(lB, 32);

    // ---- merge 4 kv-splits (private regions dead; barriers fine here) ----
    float* red_m = reinterpret_cast<float*>(smem + 34816);   // [4][64]
    float* red_l = reinterpret_cast<float*>(smem + 35840);   // [4][64]
    const int rowA = qg * 32 + lo, rowB = qg * 32 + 16 + lo;
    __syncthreads();   // all waves done with compute before smem reuse
    if (hi == 0) {
        red_m[ksp * 64 + rowA] = mA; red_l[ksp * 64 + rowA] = lA;
        red_m[ksp * 64 + rowB] = mB; red_l[ksp * 64 + rowB] = lB;
    }
    __syncthreads();
    float facA, facB;
    {
        float M = -1e30f, L = 0.f;
#pragma unroll
        for (int s = 0; s < 4; ++s) M = fmaxf(M, red_m[s * 64 + rowA]);
#pragma unroll
        for (int s = 0; s < 4; ++s) L += red_l[s * 64 + rowA] * exp2_raw(red_m[s * 64 + rowA] - M);
        facA = exp2_raw(mA - M) / L;
        M = -1e30f; L = 0.f;
#pragma unroll
        for (int s = 0; s < 4; ++s) M = fmaxf(M, red_m[s * 64 + rowB]);
#pragma unroll
        for (int s = 0; s < 4; ++s) L += red_l[s * 64 + rowB] * exp2_raw(red_m[s * 64 + rowB] - M);
        facB = exp2_raw(mB - M) / L;
    }
    float* out_lds = reinterpret_cast<float*>(smem);  // [64][132] fp32 = 33792B
    for (int s = 0; s < 4; ++s) {
        if (ksp == s) {
#pragma unroll
            for (int dt = 0; dt < 8; ++dt)
#pragma unroll
                for (int r = 0; r < 4; ++r) {
                    int d = dt * 16 + hi * 4 + r;
                    float vA = accA[dt][r] * facA;
                    float vB = accB[dt][r] * facB;
                    float* pA = &out_lds[rowA * 132 + d];
                    float* pB = &out_lds[rowB * 132 + d];
                    if (s == 0) { *pA = vA; *pB = vB; }
                    else        { *pA += vA; *pB += vB; }
                }
        }
        __syncthreads();
    }
    {
        int row = tid >> 3, d0 = (tid & 7) * 16;
        float* op = out + ((size_t)b * T_SEQ + q0 + row) * 128 + d0;
#pragma unroll
        for (int j = 0; j < 4; ++j) {
            float4 v;
            v.x = out_lds[row * 132 + d0 + j * 4 + 0];
            v.y = out_lds[row * 132 + d0 + j * 4 + 1];
            v.z = out_lds[row * 132 + d0 + j * 4 + 2];
            v.w = out_lds[row * 132 + d0 + j * 4 + 3];
            *reinterpret_cast<float4*>(op + j * 4) = v;
        }
    }
}

extern "C" void kernel_launch(void* const* d_in, const int* in_sizes, int n_in,
                              void* d_out, int out_size, void* d_ws, size_t ws_size,
                              hipStream_t stream)
{
    (void)in_sizes; (void)n_in; (void)out_size; (void)ws_size;
    const float* x  = (const float*)d_in[0];
    const float* Wq = (const float*)d_in[1];
    const float* bq = (const float*)d_in[2];
    const float* Wk = (const float*)d_in[3];
    const float* bk = (const float*)d_in[4];
    const float* Wv = (const float*)d_in[5];
    const float* bv = (const float*)d_in[6];
    float* out = (float*)d_out;

    _Float16* qf = (_Float16*)d_ws;
    _Float16* kf = qf + (size_t)4 * T_SEQ * D_HEAD;
    _Float16* vt = kf + (size_t)4 * T_SEQ * D_HEAD;

    proj_kernel<<<dim3(256, 3), 256, 0, stream>>>(x, Wq, bq, Wk, bk, Wv, bv, qf, kf, vt);
    attn_kernel<<<dim3(256), 512, 0, stream>>>(qf, kf, vt, out);
}

// Round 15
// 76.195 us; speedup vs baseline: 1.3338x; 1.3338x over previous
//
#include <hip/hip_runtime.h>
#include <cstdint>

typedef _Float16 half2_t __attribute__((ext_vector_type(2)));
typedef _Float16 half4_t __attribute__((ext_vector_type(4)));
typedef _Float16 half8_t __attribute__((ext_vector_type(8)));
typedef float floatx4 __attribute__((ext_vector_type(4)));

#define T_SEQ 4096
#define D_HEAD 128
#define SCALE_LOG2 0.12751742526f  // log2(e)/sqrt(128), folded into q at proj time

__device__ __forceinline__ float exp2_raw(float x) {
#if __has_builtin(__builtin_amdgcn_exp2f)
    return __builtin_amdgcn_exp2f(x);   // raw v_exp_f32
#else
    return exp2f(x);
#endif
}

// ---------------- QKV projection (MFMA f16, fp32 accumulate) ----------------
// q: row-major [B*T][128], pre-scaled by log2(e)/sqrt(D).
// k: FRAGMENT-TILED kt[b][g=row/16][dc][lane(lo,hi)] of 8 halfs:
//      = K[g*16+lo][dc*32+hi*8 .. +8]      (QK A-operand, load = 1 b128/lane)
// v: FRAGMENT-TILED vtt[b][t=kv/64][ksp][dt][lane(lo,hi)] of 4 halfs:
//      = V^T[dt*16+lo][t*64+ksp*16+hi*4 .. +4]  (PV A-operand, load = 1 b64/lane)
__global__ __launch_bounds__(256) void proj_kernel(
    const float* __restrict__ x,
    const float* __restrict__ Wq, const float* __restrict__ bq,
    const float* __restrict__ Wk, const float* __restrict__ bk,
    const float* __restrict__ Wv, const float* __restrict__ bv,
    _Float16* __restrict__ qf, _Float16* __restrict__ kt, _Float16* __restrict__ vtt)
{
    __shared__ __align__(16) _Float16 Ws[128 * 136];
    __shared__ __align__(16) _Float16 xs[64 * 136];

    const int t = threadIdx.x;
    const int mat = blockIdx.y;
    const float* W = (mat == 0) ? Wq : (mat == 1) ? Wk : Wv;
    const float* bias = (mat == 0) ? bq : (mat == 1) ? bk : bv;
    const float osc = (mat == 0) ? SCALE_LOG2 : 1.0f;
    const int r0 = blockIdx.x * 64;

    {
        const int o = t >> 1;
        const int i0 = (t & 1) * 64;
        for (int jj = 0; jj < 8; ++jj) {
            floatx4 w0 = *reinterpret_cast<const floatx4*>(W + o * 128 + i0 + jj * 8);
            floatx4 w1 = *reinterpret_cast<const floatx4*>(W + o * 128 + i0 + jj * 8 + 4);
            half8_t h;
            h[0]=(_Float16)w0[0]; h[1]=(_Float16)w0[1]; h[2]=(_Float16)w0[2]; h[3]=(_Float16)w0[3];
            h[4]=(_Float16)w1[0]; h[5]=(_Float16)w1[1]; h[6]=(_Float16)w1[2]; h[7]=(_Float16)w1[3];
            *reinterpret_cast<half8_t*>(&Ws[o * 136 + i0 + jj * 8]) = h;
        }
    }
    {
        const int row = t >> 2;
        const int c0 = (t & 3) * 32;
        for (int jj = 0; jj < 4; ++jj) {
            floatx4 w0 = *reinterpret_cast<const floatx4*>(x + (size_t)(r0 + row) * 128 + c0 + jj * 8);
            floatx4 w1 = *reinterpret_cast<const floatx4*>(x + (size_t)(r0 + row) * 128 + c0 + jj * 8 + 4);
            half8_t h;
            h[0]=(_Float16)w0[0]; h[1]=(_Float16)w0[1]; h[2]=(_Float16)w0[2]; h[3]=(_Float16)w0[3];
            h[4]=(_Float16)w1[0]; h[5]=(_Float16)w1[1]; h[6]=(_Float16)w1[2]; h[7]=(_Float16)w1[3];
            *reinterpret_cast<half8_t*>(&xs[row * 136 + c0 + jj * 8]) = h;
        }
    }
    __syncthreads();

    const int w = t >> 6;
    const int lane = t & 63;
    const int lo = lane & 15, hi = lane >> 4;

    floatx4 acc[8] = {};
    for (int dc = 0; dc < 4; ++dc) {
        half8_t a8 = *reinterpret_cast<const half8_t*>(&xs[(w * 16 + lo) * 136 + dc * 32 + hi * 8]);
        for (int ot = 0; ot < 8; ++ot) {
            half8_t b8 = *reinterpret_cast<const half8_t*>(&Ws[(ot * 16 + lo) * 136 + dc * 32 + hi * 8]);
            acc[ot] = __builtin_amdgcn_mfma_f32_16x16x32_f16(a8, b8, acc[ot], 0, 0, 0);
        }
    }
    __syncthreads();

    float bb[8];
    for (int ot = 0; ot < 8; ++ot) bb[ot] = bias[ot * 16 + lo];

    if (mat < 2) {
        _Float16* ol = xs;  // [64][136] row-major staging
        for (int ot = 0; ot < 8; ++ot)
            for (int r = 0; r < 4; ++r)
                ol[(w * 16 + hi * 4 + r) * 136 + ot * 16 + lo] = (_Float16)((acc[ot][r] + bb[ot]) * osc);
        __syncthreads();
        if (mat == 0) {
            for (int i = 0; i < 4; ++i) {
                int c = t + 256 * i;
                int row = c >> 4, p = c & 15;
                half8_t v = *reinterpret_cast<const half8_t*>(&ol[row * 136 + p * 8]);
                *reinterpret_cast<half8_t*>(qf + (size_t)(r0 + row) * 128 + p * 8) = v;
            }
        } else {
            // fragment-tiled K: kt[((g*4 + dc)*64 + lane)*8], g = (r0>>4)+grp
            for (int i = 0; i < 4; ++i) {
                int c = t + 256 * i;           // 0..1023
                int grp = c >> 8;              // 0..3
                int dcc = (c >> 6) & 3;
                int ln = c & 63;
                int llo = ln & 15, lhi = ln >> 4;
                half8_t v = *reinterpret_cast<const half8_t*>(&ol[(grp * 16 + llo) * 136 + dcc * 32 + lhi * 8]);
                size_t idx = ((((size_t)(r0 >> 4) + grp) * 4 + dcc) * 64 + ln) * 8;
                *reinterpret_cast<half8_t*>(kt + idx) = v;
            }
        }
    } else {
        _Float16* vl = Ws;  // [128][72] d-major staging
        for (int ot = 0; ot < 8; ++ot)
            for (int r = 0; r < 4; ++r)
                vl[(ot * 16 + lo) * 72 + w * 16 + hi * 4 + r] = (_Float16)(acc[ot][r] + bb[ot]);
        __syncthreads();
        // fragment-tiled V: vtt[(((tt*4 + ksp)*8 + dt)*64 + lane)*4], tt = r0>>6
        for (int i = 0; i < 8; ++i) {
            int c = t + 256 * i;               // 0..2047
            int kspc = c >> 9;                 // 0..3
            int dtc = (c >> 6) & 7;
            int ln = c & 63;
            int llo = ln & 15, lhi = ln >> 4;
            half4_t v = *reinterpret_cast<const half4_t*>(&vl[(dtc * 16 + llo) * 72 + kspc * 16 + lhi * 4]);
            size_t idx = ((((size_t)(r0 >> 6) * 4 + kspc) * 8 + dtc) * 64 + ln) * 4;
            *reinterpret_cast<half4_t*>(vtt + idx) = v;
        }
    }
}

// ---------------- flash attention: LDS-free fragment streaming ----------------
// 256 blocks x 512 threads = 8 waves: 2 q-groups (32 q as 2x16) x 4 kv-splits (16 kv).
// K and V^T live in global memory in fragment order -> per 64-kv tile a wave issues
// 4 b128 (K) + 8 b64 (V) perfectly-coalesced L2 loads into REGISTERS, double-buffered
// one tile ahead. ZERO LDS ops and ZERO barriers in the main loop. PV runs same-tile.
__global__ __launch_bounds__(512, 2) void attn_kernel(
    const _Float16* __restrict__ qf, const _Float16* __restrict__ kt,
    const _Float16* __restrict__ vtt, float* __restrict__ out)
{
    __shared__ __align__(16) float out_lds[64 * 132];   // merge only (33792B)
    __shared__ float red_m[4 * 64], red_l[4 * 64];

    const int tid = threadIdx.x;
    const int w = tid >> 6, lane = tid & 63;
    const int lo = lane & 15, hi = lane >> 4;
    const int qg = w & 1, ksp = w >> 1;

    // XCD-aware swizzle: 32 consecutive wg per XCD -> one batch's K/V per XCD L2
    const int bx = blockIdx.x;
    const int wg = (bx & 7) * 32 + (bx >> 3);
    const int b = wg >> 6;
    const int q0 = (wg & 63) * 64;

    // fragment bases (1MB per batch each); per-tile stride 16384B
    const char* ktb = (const char*)kt + ((size_t)b << 20) + ksp * 4096 + lane * 16;
    const char* vtb = (const char*)vtt + ((size_t)b << 20) + ksp * 4096 + lane * 8;

    // Q fragments (pre-scaled): d-enum dc*32+hi*8+j, matches kt's fragment order
    half8_t qfA[4], qfB[4];
    {
        const _Float16* qa = qf + ((size_t)b * T_SEQ + q0 + qg * 32 + lo) * 128;
        const _Float16* qb = qa + 16 * 128;
#pragma unroll
        for (int dc = 0; dc < 4; ++dc) {
            qfA[dc] = *reinterpret_cast<const half8_t*>(qa + dc * 32 + hi * 8);
            qfB[dc] = *reinterpret_cast<const half8_t*>(qb + dc * 32 + hi * 8);
        }
    }

    floatx4 accA[8] = {}, accB[8] = {};
    float mA = -1e30f, mB = -1e30f, lA = 0.f, lB = 0.f;   // l is LANE-PARTIAL
    half8_t k0[4], k1[4];
    half4_t v0[8], v1[8];

    // prologue: tile 0 -> set 0
#pragma unroll
    for (int dc = 0; dc < 4; ++dc)
        k0[dc] = *reinterpret_cast<const half8_t*>(ktb + dc * 1024);
#pragma unroll
    for (int dt = 0; dt < 8; ++dt)
        v0[dt] = *reinterpret_cast<const half4_t*>(vtb + dt * 512);

    // Per tile t: [issue K(t+1),V(t+1) -> other reg set] [QK(t)] [lane-local
    // defer-max softmax] [pa] [PV(t) same-tile]. Compiler inserts counted vmcnt
    // for the register deps; loads stay in flight across one full tile of compute.
#define TILE(T0, KC, VC, KN, VN, PF) do {                                              \
    if (PF) {                                                                          \
        const char* kp = ktb + (size_t)((T0) + 1) * 16384;                             \
        _Pragma("unroll")                                                              \
        for (int dc = 0; dc < 4; ++dc)                                                 \
            KN[dc] = *reinterpret_cast<const half8_t*>(kp + dc * 1024);                \
        const char* vp = vtb + (size_t)((T0) + 1) * 16384;                             \
        _Pragma("unroll")                                                              \
        for (int dt = 0; dt < 8; ++dt)                                                 \
            VN[dt] = *reinterpret_cast<const half4_t*>(vp + dt * 512);                 \
    }                                                                                  \
    floatx4 sA = {0.f,0.f,0.f,0.f}, sB = {0.f,0.f,0.f,0.f};                            \
    __builtin_amdgcn_s_setprio(1);                                                     \
    _Pragma("unroll")                                                                  \
    for (int dc = 0; dc < 4; ++dc) {                                                   \
        sA = __builtin_amdgcn_mfma_f32_16x16x32_f16(KC[dc], qfA[dc], sA, 0, 0, 0);     \
        sB = __builtin_amdgcn_mfma_f32_16x16x32_f16(KC[dc], qfB[dc], sB, 0, 0, 0);     \
    }                                                                                  \
    __builtin_amdgcn_s_setprio(0);                                                     \
    float mpA = fmaxf(fmaxf(sA[0], sA[1]), fmaxf(sA[2], sA[3]));                       \
    float mpB = fmaxf(fmaxf(sB[0], sB[1]), fmaxf(sB[2], sB[3]));                       \
    bool ok = (mpA <= mA + 4.0f) && (mpB <= mB + 4.0f);                                \
    if (!__all(ok)) {                                                                  \
        float ra = mpA, rb = mpB;                                                      \
        ra = fmaxf(ra, __shfl_xor(ra, 16)); ra = fmaxf(ra, __shfl_xor(ra, 32));        \
        rb = fmaxf(rb, __shfl_xor(rb, 16)); rb = fmaxf(rb, __shfl_xor(rb, 32));        \
        float nA = fmaxf(mA, ra), nB = fmaxf(mB, rb);                                  \
        float aA = exp2_raw(mA - nA), aB = exp2_raw(mB - nB);                          \
        lA *= aA; lB *= aB;                                                            \
        _Pragma("unroll")                                                              \
        for (int dt = 0; dt < 8; ++dt) { accA[dt] *= aA; accB[dt] *= aB; }             \
        mA = nA; mB = nB;                                                              \
    }                                                                                  \
    half4_t paA, paB;                                                                  \
    {                                                                                  \
        float p0 = exp2_raw(sA[0] - mA), p1 = exp2_raw(sA[1] - mA);                    \
        float p2 = exp2_raw(sA[2] - mA), p3 = exp2_raw(sA[3] - mA);                    \
        lA += (p0 + p1) + (p2 + p3);                                                   \
        half2_t h0 = __builtin_bit_cast(half2_t, __builtin_amdgcn_cvt_pkrtz(p0, p1));  \
        half2_t h1 = __builtin_bit_cast(half2_t, __builtin_amdgcn_cvt_pkrtz(p2, p3));  \
        paA[0] = h0[0]; paA[1] = h0[1]; paA[2] = h1[0]; paA[3] = h1[1];                \
        p0 = exp2_raw(sB[0] - mB); p1 = exp2_raw(sB[1] - mB);                          \
        p2 = exp2_raw(sB[2] - mB); p3 = exp2_raw(sB[3] - mB);                          \
        lB += (p0 + p1) + (p2 + p3);                                                   \
        h0 = __builtin_bit_cast(half2_t, __builtin_amdgcn_cvt_pkrtz(p0, p1));          \
        h1 = __builtin_bit_cast(half2_t, __builtin_amdgcn_cvt_pkrtz(p2, p3));          \
        paB[0] = h0[0]; paB[1] = h0[1]; paB[2] = h1[0]; paB[3] = h1[1];                \
    }                                                                                  \
    __builtin_amdgcn_s_setprio(1);                                                     \
    _Pragma("unroll")                                                                  \
    for (int dt = 0; dt < 8; ++dt) {                                                   \
        accA[dt] = __builtin_amdgcn_mfma_f32_16x16x16f16(VC[dt], paA, accA[dt], 0, 0, 0); \
        accB[dt] = __builtin_amdgcn_mfma_f32_16x16x16f16(VC[dt], paB, accB[dt], 0, 0, 0); \
    }                                                                                  \
    __builtin_amdgcn_s_setprio(0);                                                     \
} while (0)

    // 64 tiles of 64 kv; register sets alternate by parity.
    for (int tt = 0; tt < 62; tt += 2) {
        TILE(tt,     k0, v0, k1, v1, 1);
        TILE(tt + 1, k1, v1, k0, v0, 1);
    }
    TILE(62, k0, v0, k1, v1, 1);
    TILE(63, k1, v1, k0, v0, 0);
#undef TILE

    // reduce lane-partial l across hi-groups (once)
    lA += __shfl_xor(lA, 16); lA += __shfl_xor(lA, 32);
    lB += __shfl_xor(lB, 16); lB += __shfl_xor(lB, 32);

    // ---- merge 4 kv-splits ----
    const int rowA = qg * 32 + lo, rowB = qg * 32 + 16 + lo;
    if (hi == 0) {
        red_m[ksp * 64 + rowA] = mA; red_l[ksp * 64 + rowA] = lA;
        red_m[ksp * 64 + rowB] = mB; red_l[ksp * 64 + rowB] = lB;
    }
    __syncthreads();
    float facA, facB;
    {
        float M = -1e30f, L = 0.f;
#pragma unroll
        for (int s = 0; s < 4; ++s) M = fmaxf(M, red_m[s * 64 + rowA]);
#pragma unroll
        for (int s = 0; s < 4; ++s) L += red_l[s * 64 + rowA] * exp2_raw(red_m[s * 64 + rowA] - M);
        facA = exp2_raw(mA - M) / L;
        M = -1e30f; L = 0.f;
#pragma unroll
        for (int s = 0; s < 4; ++s) M = fmaxf(M, red_m[s * 64 + rowB]);
#pragma unroll
        for (int s = 0; s < 4; ++s) L += red_l[s * 64 + rowB] * exp2_raw(red_m[s * 64 + rowB] - M);
        facB = exp2_raw(mB - M) / L;
    }
    for (int s = 0; s < 4; ++s) {
        if (ksp == s) {
#pragma unroll
            for (int dt = 0; dt < 8; ++dt)
#pragma unroll
                for (int r = 0; r < 4; ++r) {
                    int d = dt * 16 + hi * 4 + r;
                    float vA = accA[dt][r] * facA;
                    float vB = accB[dt][r] * facB;
                    float* pA = &out_lds[rowA * 132 + d];
                    float* pB = &out_lds[rowB * 132 + d];
                    if (s == 0) { *pA = vA; *pB = vB; }
                    else        { *pA += vA; *pB += vB; }
                }
        }
        __syncthreads();
    }
    {
        int row = tid >> 3, d0 = (tid & 7) * 16;
        float* op = out + ((size_t)b * T_SEQ + q0 + row) * 128 + d0;
#pragma unroll
        for (int j = 0; j < 4; ++j) {
            float4 v;
            v.x = out_lds[row * 132 + d0 + j * 4 + 0];
            v.y = out_lds[row * 132 + d0 + j * 4 + 1];
            v.z = out_lds[row * 132 + d0 + j * 4 + 2];
            v.w = out_lds[row * 132 + d0 + j * 4 + 3];
            *reinterpret_cast<float4*>(op + j * 4) = v;
        }
    }
}

extern "C" void kernel_launch(void* const* d_in, const int* in_sizes, int n_in,
                              void* d_out, int out_size, void* d_ws, size_t ws_size,
                              hipStream_t stream)
{
    (void)in_sizes; (void)n_in; (void)out_size; (void)ws_size;
    const float* x  = (const float*)d_in[0];
    const float* Wq = (const float*)d_in[1];
    const float* bq = (const float*)d_in[2];
    const float* Wk = (const float*)d_in[3];
    const float* bk = (const float*)d_in[4];
    const float* Wv = (const float*)d_in[5];
    const float* bv = (const float*)d_in[6];
    float* out = (float*)d_out;

    // workspace: q 4MB | kt (fragment-tiled K) 4MB | vtt (fragment-tiled V^T) 4MB
    _Float16* qf  = (_Float16*)d_ws;
    _Float16* kt  = qf + (size_t)4 * T_SEQ * D_HEAD;
    _Float16* vtt = kt + (size_t)4 * T_SEQ * D_HEAD;

    proj_kernel<<<dim3(256, 3), 256, 0, stream>>>(x, Wq, bq, Wk, bk, Wv, bv, qf, kt, vtt);
    attn_kernel<<<dim3(256), 512, 0, stream>>>(qf, kt, vtt, out);
}